// Round 1
// baseline (309.996 us; speedup 1.0000x reference)
//
#include <hip/hip_runtime.h>
#include <math.h>
#include <float.h>

// Problem constants
constexpr int CB = 16;        // batch
constexpr int CC = 256;       // channels
constexpr int PH = 96, PW = 96, PHW = 9216;
constexpr int MH = 48, MW = 48, MHW = 2304;
constexpr int KSPLIT = 2;
constexpr int KHALF = 1152;   // MHW / KSPLIT
constexpr int KTILE = 32;

__device__ __forceinline__ float sigmoidf_(float x) { return 1.f / (1.f + __expf(-x)); }

__device__ __forceinline__ unsigned f2ord(float f) {
  unsigned u = __float_as_uint(f);
  return (u & 0x80000000u) ? ~u : (u | 0x80000000u);
}

// ---------------- Kernel A: f_p stats + bilinear-adjoint downsample ----------------
__global__ __launch_bounds__(256) void k_pstats(const float* __restrict__ fp,
                                                float* __restrict__ padj,
                                                float* __restrict__ meanp,
                                                float* __restrict__ pn) {
  __shared__ __align__(16) float sm[PHW];       // 36 KB
  __shared__ __align__(16) float tmp[MH * PW];  // 18 KB
  __shared__ float rs[4], rss[4];
  const int bc = blockIdx.x;
  const int tid = threadIdx.x;
  const float* img = fp + (size_t)bc * PHW;
  float s = 0.f, ss = 0.f;
  for (int q = tid; q < PHW / 4; q += 256) {
    float4 v = ((const float4*)img)[q];
    ((float4*)sm)[q] = v;
    s += v.x + v.y + v.z + v.w;
    ss += v.x * v.x + v.y * v.y + v.z * v.z + v.w * v.w;
  }
  for (int off = 32; off; off >>= 1) { s += __shfl_down(s, off); ss += __shfl_down(ss, off); }
  if ((tid & 63) == 0) { rs[tid >> 6] = s; rss[tid >> 6] = ss; }
  __syncthreads();
  if (tid == 0) {
    float S = rs[0] + rs[1] + rs[2] + rs[3];
    float SS = rss[0] + rss[1] + rss[2] + rss[3];
    meanp[bc] = S / (float)PHW;
    pn[bc] = sqrtf(fmaxf(SS - S * S / (float)PHW, 0.f));
  }
  // row adjoint: tmp[u][w] = sum_h Wrow[h,u] * p[h,w]
  for (int i = tid; i < MH * PW; i += 256) {
    int u = i / PW, w = i - u * PW;
    float v;
    if (u == 0)
      v = sm[w] + 0.75f * sm[PW + w] + 0.25f * sm[2 * PW + w];
    else if (u == MH - 1)
      v = 0.25f * sm[(PH - 3) * PW + w] + 0.75f * sm[(PH - 2) * PW + w] + sm[(PH - 1) * PW + w];
    else
      v = 0.25f * (sm[(2 * u - 1) * PW + w] + sm[(2 * u + 2) * PW + w]) +
          0.75f * (sm[2 * u * PW + w] + sm[(2 * u + 1) * PW + w]);
    tmp[i] = v;
  }
  __syncthreads();
  float* outp = padj + (size_t)bc * MHW;
  for (int i = tid; i < MHW; i += 256) {
    int u = i / MW, v = i - u * MW;
    const float* r = tmp + u * PW;
    float val;
    if (v == 0)
      val = r[0] + 0.75f * r[1] + 0.25f * r[2];
    else if (v == MW - 1)
      val = 0.25f * r[PW - 3] + 0.75f * r[PW - 2] + r[PW - 1];
    else
      val = 0.25f * (r[2 * v - 1] + r[2 * v + 2]) + 0.75f * (r[2 * v] + r[2 * v + 1]);
    outp[i] = val;
  }
}

// ---------------- Kernel B: f_ms stats (mean + norm of centered upsampled) ----------------
__device__ __forceinline__ void taps96(int h, int& i0, int& i1, float& w0, float& w1) {
  if (h == 0) { i0 = 0; i1 = 0; w0 = 1.f; w1 = 0.f; }
  else if (h == 95) { i0 = 47; i1 = 47; w0 = 1.f; w1 = 0.f; }
  else if (h & 1) { int k = h >> 1; i0 = k; i1 = k + 1; w0 = 0.75f; w1 = 0.25f; }
  else { int k = h >> 1; i0 = k - 1; i1 = k; w0 = 0.25f; w1 = 0.75f; }
}

__global__ __launch_bounds__(256) void k_msstats(const float* __restrict__ fms,
                                                 float* __restrict__ meanms,
                                                 float* __restrict__ msn) {
  __shared__ __align__(16) float sm[MHW];  // 9 KB
  __shared__ float rs[4], rss[4];
  const int bc = blockIdx.x, tid = threadIdx.x;
  const float* img = fms + (size_t)bc * MHW;
  float s = 0.f;
  for (int q = tid; q < MHW / 4; q += 256) {
    float4 v = ((const float4*)img)[q];
    ((float4*)sm)[q] = v;
    s += v.x + v.y + v.z + v.w;
  }
  for (int off = 32; off; off >>= 1) s += __shfl_down(s, off);
  if ((tid & 63) == 0) rs[tid >> 6] = s;
  __syncthreads();
  const float mean = (rs[0] + rs[1] + rs[2] + rs[3]) / (float)MHW;  // == mean of upsampled
  float ss = 0.f;
  for (int i = tid; i < PHW; i += 256) {
    int h = i / PW, w = i - h * PW;
    int r0, r1, c0, c1; float wr0, wr1, wc0, wc1;
    taps96(h, r0, r1, wr0, wr1);
    taps96(w, c0, c1, wc0, wc1);
    float v = wr0 * (wc0 * sm[r0 * MW + c0] + wc1 * sm[r0 * MW + c1]) +
              wr1 * (wc0 * sm[r1 * MW + c0] + wc1 * sm[r1 * MW + c1]);
    ss += v * v;
  }
  for (int off = 32; off; off >>= 1) ss += __shfl_down(ss, off);
  if ((tid & 63) == 0) rss[tid >> 6] = ss;
  __syncthreads();
  if (tid == 0) {
    float SS = rss[0] + rss[1] + rss[2] + rss[3];
    meanms[bc] = mean;
    msn[bc] = sqrtf(fmaxf(SS - (float)PHW * mean * mean, 0.f));
  }
}

// ---------------- Kernel C: batched fp32 GEMM  dot[ks][b][i][j] = sum_k ms[b,i,k]*padj[b,j,k] ----------------
__global__ __launch_bounds__(256) void k_gemm(const float* __restrict__ A,
                                              const float* __restrict__ Bm,
                                              float* __restrict__ Cp) {
  __shared__ __align__(16) float At[KTILE][68];
  __shared__ __align__(16) float Bt[KTILE][68];
  const int b = blockIdx.z >> 1, ks = blockIdx.z & 1;
  const int i0 = blockIdx.x * 64, j0 = blockIdx.y * 64;
  const int tid = threadIdx.x;
  const int ty = tid >> 4, tx = tid & 15;
  const float* Ab = A + ((size_t)b * CC + i0) * MHW + ks * KHALF;
  const float* Bb = Bm + ((size_t)b * CC + j0) * MHW + ks * KHALF;
  float acc[4][4] = {};
  for (int kt = 0; kt < KHALF; kt += KTILE) {
#pragma unroll
    for (int qq = 0; qq < 2; ++qq) {
      int q = tid + qq * 256;
      int row = q >> 3, k4 = (q & 7) << 2;
      float4 va = *(const float4*)(Ab + (size_t)row * MHW + kt + k4);
      At[k4 + 0][row] = va.x; At[k4 + 1][row] = va.y; At[k4 + 2][row] = va.z; At[k4 + 3][row] = va.w;
      float4 vb = *(const float4*)(Bb + (size_t)row * MHW + kt + k4);
      Bt[k4 + 0][row] = vb.x; Bt[k4 + 1][row] = vb.y; Bt[k4 + 2][row] = vb.z; Bt[k4 + 3][row] = vb.w;
    }
    __syncthreads();
#pragma unroll
    for (int k = 0; k < KTILE; ++k) {
      float a[4], bb[4];
      *(float4*)a = *(const float4*)&At[k][ty * 4];
      *(float4*)bb = *(const float4*)&Bt[k][tx * 4];
#pragma unroll
      for (int u = 0; u < 4; ++u)
#pragma unroll
        for (int v = 0; v < 4; ++v)
          acc[u][v] = fmaf(a[u], bb[v], acc[u][v]);
    }
    __syncthreads();
  }
  float* outp = Cp + (((size_t)ks * CB + b) * CC + (i0 + ty * 4)) * CC + j0 + tx * 4;
#pragma unroll
  for (int u = 0; u < 4; ++u)
    *(float4*)(outp + (size_t)u * CC) = make_float4(acc[u][0], acc[u][1], acc[u][2], acc[u][3]);
}

// ---------------- Kernel C2: per-row max/argmax of similarity ----------------
__global__ __launch_bounds__(256) void k_rowmax(const float* __restrict__ dotp,
                                                const float* __restrict__ meanp,
                                                const float* __restrict__ pn,
                                                const float* __restrict__ meanms,
                                                const float* __restrict__ msn,
                                                float* __restrict__ maxv,
                                                int* __restrict__ amax) {
  const int tid = threadIdx.x;
  const int r = blockIdx.x * 4 + (tid >> 6);  // row in [0, CB*CC)
  const int lane = tid & 63;
  const int b = r >> 8;
  const float* d0 = dotp + (size_t)r * CC;
  const float* d1 = d0 + (size_t)CB * CC * CC;
  const float mm = meanms[r];
  const float inv = 100.f / msn[r];
  const int j = lane * 4;
  float4 v0 = *(const float4*)(d0 + j);
  float4 v1 = *(const float4*)(d1 + j);
  float4 mp4 = *(const float4*)(meanp + b * CC + j);
  float4 pn4 = *(const float4*)(pn + b * CC + j);
  float sv[4];
  sv[0] = (v0.x + v1.x - (float)PHW * mm * mp4.x) * inv / pn4.x;
  sv[1] = (v0.y + v1.y - (float)PHW * mm * mp4.y) * inv / pn4.y;
  sv[2] = (v0.z + v1.z - (float)PHW * mm * mp4.z) * inv / pn4.z;
  sv[3] = (v0.w + v1.w - (float)PHW * mm * mp4.w) * inv / pn4.w;
  float best = sv[0]; int bj = j;
#pragma unroll
  for (int t = 1; t < 4; ++t)
    if (sv[t] > best) { best = sv[t]; bj = j + t; }
  for (int off = 32; off; off >>= 1) {
    float ov = __shfl_down(best, off);
    int oi = __shfl_down(bj, off);
    if (ov > best || (ov == best && oi < bj)) { best = ov; bj = oi; }
  }
  if (lane == 0) { maxv[r] = best; amax[r] = bj; }
}

// ---------------- Kernel D: group select + deterministic bitonic sort (per batch) ----------------
__global__ __launch_bounds__(256) void k_group(const float* __restrict__ maxv,
                                               const int* __restrict__ amax,
                                               float* __restrict__ sscore,
                                               int* __restrict__ svals,
                                               int* __restrict__ cnt) {
  const int b = blockIdx.x, tid = threadIdx.x;
  __shared__ float mv[CC];
  __shared__ int sidx[CC];
  __shared__ float gsc[CC];
  __shared__ int pres[CC];
  __shared__ unsigned long long keys[CC];
  __shared__ float r1[4], r2[4];
  __shared__ int r3[4];
  float v = maxv[b * CC + tid];
  sidx[tid] = amax[b * CC + tid];
  float m = v;
  for (int off = 32; off; off >>= 1) m = fmaxf(m, __shfl_down(m, off));
  if ((tid & 63) == 0) r1[tid >> 6] = m;
  __syncthreads();
  float mt = fmaxf(fmaxf(r1[0], r1[1]), fmaxf(r1[2], r1[3]));
  float e = __expf(v - mt);
  float s = e;
  for (int off = 32; off; off >>= 1) s += __shfl_down(s, off);
  if ((tid & 63) == 0) r2[tid >> 6] = s;
  __syncthreads();
  float st = r2[0] + r2[1] + r2[2] + r2[3];
  mv[tid] = e / st;
  __syncthreads();
  // group score for channel j = tid (sequential over i -> deterministic)
  float g = 0.f; int p = 0;
  for (int i2 = 0; i2 < CC; ++i2)
    if (sidx[i2] == tid) { g += mv[i2]; p = 1; }
  gsc[tid] = g; pres[tid] = p;
  int pc = p;
  for (int off = 32; off; off >>= 1) pc += __shfl_down(pc, off);
  if ((tid & 63) == 0) r3[tid >> 6] = pc;
  __syncthreads();
  if (tid == 0) cnt[b] = r3[0] + r3[1] + r3[2] + r3[3];
  // key: (ordered score << 32) | channel; descending sort => ties -> larger channel first
  int c = 255 - tid;
  float val = pres[c] ? gsc[c] : -INFINITY;
  keys[tid] = ((unsigned long long)f2ord(val) << 32) | (unsigned)c;
  __syncthreads();
  for (int ksz = 2; ksz <= 256; ksz <<= 1) {
    for (int jj = ksz >> 1; jj > 0; jj >>= 1) {
      int ixj = tid ^ jj;
      if (ixj > tid) {
        unsigned long long a = keys[tid], o = keys[ixj];
        bool descBlock = ((tid & ksz) == 0);
        bool sw = descBlock ? (a < o) : (a > o);
        if (sw) { keys[tid] = o; keys[ixj] = a; }
      }
      __syncthreads();
    }
  }
  unsigned long long kk = keys[tid];
  int cc2 = (int)(kk & 0xFFFFFFFFull);
  float vv = pres[cc2] ? gsc[cc2] : -INFINITY;
  sscore[b * CC + tid] = vv;
  svals[b * CC + tid] = cc2;
}

// ---------------- Kernel E: min_k + softmax weights ----------------
__global__ __launch_bounds__(128) void k_wsel(const float* __restrict__ sscore,
                                              const int* __restrict__ cnt,
                                              float* __restrict__ wgt,
                                              int* __restrict__ minkp) {
  const int b = blockIdx.x, tid = threadIdx.x;
  int mn = 0x7fffffff;
#pragma unroll
  for (int t = 0; t < CB; ++t) mn = min(mn, cnt[t]);
  const int mink = (mn + 1) >> 1;
  if (b == 0 && tid == 0) *minkp = mink;
  __shared__ float sh1[2], sh2[2];
  float v = (tid < mink) ? sscore[b * CC + tid] : -INFINITY;
  float m = v;
  for (int off = 32; off; off >>= 1) m = fmaxf(m, __shfl_down(m, off));
  if ((tid & 63) == 0) sh1[tid >> 6] = m;
  __syncthreads();
  float mt = fmaxf(sh1[0], sh1[1]);
  float e = (tid < mink) ? __expf(v - mt) : 0.f;
  float s = e;
  for (int off = 32; off; off >>= 1) s += __shfl_down(s, off);
  if ((tid & 63) == 0) sh2[tid >> 6] = s;
  __syncthreads();
  float st = sh2[0] + sh2[1];
  if (tid < mink) wgt[b * 128 + tid] = e / st;
}

// ---------------- Kernel F1: mask[b,hw] = sum_k w[b,k]*sigmoid(fp[b,sel[k],hw]) ----------------
__global__ __launch_bounds__(256) void k_mask(const float* __restrict__ fp,
                                              const float* __restrict__ wgt,
                                              const int* __restrict__ svals,
                                              const int* __restrict__ minkp,
                                              float* __restrict__ mask) {
  const int b = blockIdx.y;
  const int hw4 = blockIdx.x * 256 + threadIdx.x;  // float4 index < 2304
  const int mink = *minkp;
  const float* base = fp + (size_t)b * CC * PHW;
  float4 acc = make_float4(0.f, 0.f, 0.f, 0.f);
  for (int k = 0; k < mink; ++k) {
    int c = svals[b * CC + k];
    float wk = wgt[b * 128 + k];
    float4 v = ((const float4*)(base + (size_t)c * PHW))[hw4];
    acc.x += wk * sigmoidf_(v.x);
    acc.y += wk * sigmoidf_(v.y);
    acc.z += wk * sigmoidf_(v.z);
    acc.w += wk * sigmoidf_(v.w);
  }
  ((float4*)(mask + (size_t)b * PHW))[hw4] = acc;
}

// ---------------- Kernel F2: out = fp * (1 + mask) ----------------
__global__ __launch_bounds__(256) void k_out(const float* __restrict__ fp,
                                             const float* __restrict__ mask,
                                             float* __restrict__ out) {
  const int idx = blockIdx.x * 256 + threadIdx.x;  // float4 index
  const int img = idx / (PHW / 4);
  const int hw4 = idx - img * (PHW / 4);
  const int b = img >> 8;
  float4 mk = ((const float4*)mask)[b * (PHW / 4) + hw4];
  float4 v = ((const float4*)fp)[idx];
  float4 o;
  o.x = v.x * (1.f + mk.x);
  o.y = v.y * (1.f + mk.y);
  o.z = v.z * (1.f + mk.z);
  o.w = v.w * (1.f + mk.w);
  ((float4*)out)[idx] = o;
}

extern "C" void kernel_launch(void* const* d_in, const int* in_sizes, int n_in,
                              void* d_out, int out_size, void* d_ws, size_t ws_size,
                              hipStream_t stream) {
  (void)in_sizes; (void)n_in; (void)out_size;
  const float* fp = (const float*)d_in[0];
  const float* fms = (const float*)d_in[1];
  float* out = (float*)d_out;

  // Big scratch lives in d_out (dead before k_out overwrites it):
  //   padj: 16*256*2304 = 9,437,184 floats
  //   dot : 2*16*256*256 = 2,097,152 floats
  float* padj = out;
  float* dotp = out + (size_t)CB * CC * MHW;

  // Small scratch in d_ws (~730 KB)
  if (ws_size < (size_t)183000 * 4) return;
  float* wsf = (float*)d_ws;
  float* meanp = wsf;               // 4096
  float* pnv = wsf + 4096;          // 4096
  float* meanms = wsf + 8192;       // 4096
  float* msn = wsf + 12288;         // 4096
  float* maxv = wsf + 16384;        // 4096
  float* ssc = wsf + 20480;         // 4096
  float* wgt = wsf + 24576;         // 2048
  float* maskp = wsf + 26624;       // 147456 -> ends at 174080
  int* amax = (int*)(wsf + 174080); // 4096
  int* sv = (int*)(wsf + 178176);   // 4096
  int* cntp = (int*)(wsf + 182272); // 16
  int* minkp = (int*)(wsf + 182288);// 1

  k_pstats<<<CB * CC, 256, 0, stream>>>(fp, padj, meanp, pnv);
  k_msstats<<<CB * CC, 256, 0, stream>>>(fms, meanms, msn);
  dim3 gg(4, 4, CB * KSPLIT);
  k_gemm<<<gg, 256, 0, stream>>>(fms, padj, dotp);
  k_rowmax<<<(CB * CC) / 4, 256, 0, stream>>>(dotp, meanp, pnv, meanms, msn, maxv, amax);
  k_group<<<CB, 256, 0, stream>>>(maxv, amax, ssc, sv, cntp);
  k_wsel<<<CB, 128, 0, stream>>>(ssc, cntp, wgt, minkp);
  k_mask<<<dim3(PHW / 4 / 256, CB), 256, 0, stream>>>(fp, wgt, sv, minkp, maskp);
  k_out<<<(CB * CC * PHW / 4) / 256, 256, 0, stream>>>(fp, maskp, out);
}